// Round 3
// baseline (148.573 us; speedup 1.0000x reference)
//
#include <hip/hip_runtime.h>
#include <hip/hip_bf16.h>

#define GATE 512
#define MROWS 256
#define NTOT 120581

typedef __attribute__((ext_vector_type(8))) short short8;   // 8 bf16
typedef __attribute__((ext_vector_type(4))) float  f32x4;

struct GemmParams {
    const float* W[10];
    const float* p[10];
    const float* bias[10];
};

__device__ __forceinline__ short bf16bits(float x) {
    __hip_bfloat16 h = __float2bfloat16(x);   // RTNE
    return *reinterpret_cast<short*>(&h);
}

// emb fp32 -> bf16, 8 elems/thread
__global__ void emb_to_bf16(const float* __restrict__ emb,
                            unsigned short* __restrict__ o) {
    int i = (blockIdx.x * blockDim.x + threadIdx.x) * 8;
    f32x4 a = *(const f32x4*)(emb + i);
    f32x4 b = *(const f32x4*)(emb + i + 4);
    short8 r;
#pragma unroll
    for (int j = 0; j < 4; ++j) { r[j] = bf16bits(a[j]); r[4 + j] = bf16bits(b[j]); }
    *(short8*)(o + i) = r;
}

// Block: 256 rows x 64 cols. 4 waves as 2M x 2N: wave(wm,wn) owns rows
// [wm*128,+128) x cols [wn*32,+32). A staged in LDS in K-phases of 64
// (single-buffered, 2 K-step-32 subtiles); B register-prefetched from global,
// no barrier inside a phase -> B loads get counted (not drained) waits.
__global__ __launch_bounds__(256, 4) void gate_gemm(GemmParams P,
                                                    const unsigned short* __restrict__ embw,
                                                    float* __restrict__ out)
{
    constexpr int kStarts[11] = {0, 1728, 1792, 38656, 38720, 75584,
                                 75648, 112512, 112576, 120576, 120581};
    __shared__ unsigned short Atile[2][MROWS][32];   // [sub][row][kslot] = 32 KB

    const int t    = threadIdx.x;
    const int lane = t & 63;
    const int wave = t >> 6;
    const int wm   = wave >> 1;          // M half: rows [wm*128, +128)
    const int wn   = wave & 1;           // N half: cols [wn*32, +32)
    const int lr   = lane & 15;          // frag col (B/C) / frag row (A)
    const int lg   = lane >> 4;          // k-group / C row-group

    // Per-lane column metadata, 2 N-fragments
    const float* wrow[2];
    float pv[2], bv[2];
    bool  valid[2];
    int   ncol[2];
#pragma unroll
    for (int nf = 0; nf < 2; ++nf) {
        int n  = blockIdx.x * 64 + wn * 32 + nf * 16 + lr;
        ncol[nf]  = n;
        valid[nf] = n < NTOT;
        int nc = valid[nf] ? n : NTOT - 1;
        int tt = 0;
#pragma unroll
        for (int i = 1; i < 10; ++i) tt += (nc >= kStarts[i]);
        int r = nc - kStarts[tt];
        wrow[nf] = P.W[tt] + (size_t)r * GATE + lg * 8;
        pv[nf]   = P.p[tt][r];
        bv[nf]   = P.bias[tt][r];
    }

    // A staging: pre-swizzled global source, linear LDS dest (16B units).
    // Unit l = i*256 + t -> row = l>>2, slotw = t&3; content col-slot = slotw ^ ((row>>1)&3).
    const int srow0 = t >> 2;
    const int sslot = (t & 3) ^ ((t >> 3) & 3);
    const unsigned short* asrc = embw + (size_t)srow0 * GATE + sslot * 8;
    unsigned short* sdst = &Atile[0][0][0] + (size_t)t * 8;

    auto stage = [&](int ph) {
#pragma unroll
        for (int sub = 0; sub < 2; ++sub)
#pragma unroll
            for (int i = 0; i < 4; ++i) {
                const unsigned short* src = asrc + (size_t)i * 64 * GATE + ph * 64 + sub * 32;
                unsigned short* dst = sdst + sub * 8192 + i * 2048;
                __builtin_amdgcn_global_load_lds(
                    (const __attribute__((address_space(1))) void*)src,
                    (__attribute__((address_space(3))) void*)dst, 16, 0, 0);
            }
    };

    // A read: row = wm*128 + mf*16 + lr, slot = lg ^ ((lr>>1)&3)  (2-way-free, 0 conflicts measured)
    const int aslot = lg ^ ((lr >> 1) & 3);
    const int abase = (wm * 128 + lr) * 32 + aslot * 8;   // ushort idx; + sub*8192 + mf*512

    f32x4 acc[8][2];
#pragma unroll
    for (int i = 0; i < 8; ++i)
#pragma unroll
        for (int j = 0; j < 2; ++j) acc[i][j] = (f32x4){0.f, 0.f, 0.f, 0.f};

    f32x4 Bcur[2][2], Bnxt[2][2];
    auto loadB = [&](f32x4 (&B)[2][2], int gks) {
#pragma unroll
        for (int nf = 0; nf < 2; ++nf) {
            B[nf][0] = *(const f32x4*)(wrow[nf] + gks * 32);
            B[nf][1] = *(const f32x4*)(wrow[nf] + gks * 32 + 4);
        }
    };

    // Prologue
    stage(0);
    loadB(Bcur, 0);
    __syncthreads();   // drain: Atile phase 0 + Bcur ready

    for (int ph = 0; ph < 8; ++ph) {
#pragma unroll
        for (int sub = 0; sub < 2; ++sub) {
            const int gks = ph * 2 + sub;
            if (gks < 15) loadB(Bnxt, gks + 1);   // issued early; no barrier before use

            short8 bfrag[2];
#pragma unroll
            for (int nf = 0; nf < 2; ++nf)
#pragma unroll
                for (int j = 0; j < 4; ++j) {
                    bfrag[nf][j]     = bf16bits(Bcur[nf][0][j]);
                    bfrag[nf][4 + j] = bf16bits(Bcur[nf][1][j]);
                }

            const unsigned short* ab = &Atile[0][0][0] + sub * 8192 + abase;
#pragma unroll
            for (int mf = 0; mf < 8; ++mf) {
                short8 afrag = *(const short8*)(ab + mf * 512);
                acc[mf][0] = __builtin_amdgcn_mfma_f32_16x16x32_bf16(afrag, bfrag[0], acc[mf][0], 0, 0, 0);
                acc[mf][1] = __builtin_amdgcn_mfma_f32_16x16x32_bf16(afrag, bfrag[1], acc[mf][1], 0, 0, 0);
            }

            if (gks < 15) {
#pragma unroll
                for (int nf = 0; nf < 2; ++nf) {
                    Bcur[nf][0] = Bnxt[nf][0];
                    Bcur[nf][1] = Bnxt[nf][1];
                }
            }
        }
        if (ph < 7) {
            __syncthreads();   // all waves done reading Atile (drains in-flight B too)
            stage(ph + 1);     // overwrite single buffer
            __syncthreads();   // stage drained (L2-hot A, ~short)
        }
    }

    // Epilogue: sigmoid(x + b) * p. C/D map: col = lane&15, row = (lane>>4)*4 + reg.
#pragma unroll
    for (int nf = 0; nf < 2; ++nf) {
        if (!valid[nf]) continue;
        float* ocol = out + ncol[nf];
#pragma unroll
        for (int mf = 0; mf < 8; ++mf) {
            const int m0 = wm * 128 + mf * 16 + lg * 4;
#pragma unroll
            for (int q = 0; q < 4; ++q) {
                float x   = acc[mf][nf][q] + bv[nf];
                float e   = __expf(-x);
                float eta = __builtin_amdgcn_rcpf(1.0f + e);
                ocol[(size_t)(m0 + q) * NTOT] = eta * pv[nf];
            }
        }
    }
}

extern "C" void kernel_launch(void* const* d_in, const int* in_sizes, int n_in,
                              void* d_out, int out_size, void* d_ws, size_t ws_size,
                              hipStream_t stream) {
    const float* emb = (const float*)d_in[0];
    GemmParams P;
    for (int i = 0; i < 10; ++i) {
        P.p[i]    = (const float*)d_in[1 + 3 * i];
        P.W[i]    = (const float*)d_in[2 + 3 * i];
        P.bias[i] = (const float*)d_in[3 + 3 * i];
    }

    unsigned short* embw = (unsigned short*)d_ws;   // 256 KB
    emb_to_bf16<<<(MROWS * GATE) / (256 * 8), 256, 0, stream>>>(emb, embw);

    int nblocks = (NTOT + 63) / 64;   // 1885
    gate_gemm<<<nblocks, 256, 0, stream>>>(P, embw, (float*)d_out);
}